// Round 14
// baseline (154.351 us; speedup 1.0000x reference)
//
#include <hip/hip_runtime.h>
#include <hip/hip_cooperative_groups.h>
#include <math.h>

namespace cg = cooperative_groups;

#define N_NODES 384
#define N_EDGES 1280
#define NBLOCKS 320

// ---------------------------------------------------------------------------
// Lane-exchange: DPP for xor masks 1,2,8 (VALU pipe, verified r6-r12):
//   xor1 = quad_perm [1,0,3,2]; xor2 = quad_perm [2,3,0,1]; xor8 = row_ror:8.
// Masks 4,16,32 -> __shfl_xor. Permlane swaps: BANNED (r3/r4 failures).
// ---------------------------------------------------------------------------
template <int M>
__device__ __forceinline__ float lxor_f(float x)
{
    if constexpr (M == 1) {
        return __builtin_bit_cast(float, __builtin_amdgcn_mov_dpp(
            __builtin_bit_cast(int, x), 0xB1, 0xF, 0xF, true));
    } else if constexpr (M == 2) {
        return __builtin_bit_cast(float, __builtin_amdgcn_mov_dpp(
            __builtin_bit_cast(int, x), 0x4E, 0xF, 0xF, true));
    } else if constexpr (M == 8) {
        return __builtin_bit_cast(float, __builtin_amdgcn_mov_dpp(
            __builtin_bit_cast(int, x), 0x128, 0xF, 0xF, true));
    } else {
        return __shfl_xor(x, M, 64);        // masks 4, 16, 32
    }
}

// ---------------------------------------------------------------------------
// float2-packed gate helpers (r8/r11/r12-verified algebra).
// ---------------------------------------------------------------------------
template <int K, int M>         // RY on a packed-index bit (elementwise f2)
__device__ __forceinline__ void ryr2(float2 (&a)[K], float c_, float s_)
{
#pragma unroll
    for (int k = 0; k < K; k++)
        if ((k & M) == 0) {
            float2 u = a[k], v = a[k | M];
            a[k].x     = c_ * u.x - s_ * v.x;
            a[k].y     = c_ * u.y - s_ * v.y;
            a[k | M].x = s_ * u.x + c_ * v.x;
            a[k | M].y = s_ * u.y + c_ * v.y;
        }
}

template <int K>                // RY on the component bit (x/y rotate)
__device__ __forceinline__ void ryc2(float2 (&a)[K], float c_, float s_)
{
#pragma unroll
    for (int k = 0; k < K; k++) {
        float x = a[k].x, y = a[k].y;
        a[k].x = c_ * x - s_ * y;
        a[k].y = s_ * x + c_ * y;
    }
}

template <int K, int LM>        // RY on a lane bit
__device__ __forceinline__ void ryl2(float2 (&a)[K], int lane, float c_, float s_)
{
    const float ss = (lane & LM) ? s_ : -s_;
#pragma unroll
    for (int k = 0; k < K; k++) {
        float ox = lxor_f<LM>(a[k].x);
        float oy = lxor_f<LM>(a[k].y);
        a[k].x = fmaf(ss, ox, c_ * a[k].x);
        a[k].y = fmaf(ss, oy, c_ * a[k].y);
    }
}

template <int K, int TM>        // CX, bool ctrl, lane-bit target
__device__ __forceinline__ void cxl2(float2 (&a)[K], bool ctrl)
{
#pragma unroll
    for (int k = 0; k < K; k++) {
        float ox = lxor_f<TM>(a[k].x);
        float oy = lxor_f<TM>(a[k].y);
        a[k].x = ctrl ? ox : a[k].x;
        a[k].y = ctrl ? oy : a[k].y;
    }
}

template <int K, int TM>        // CX, bool ctrl, packed-index target
__device__ __forceinline__ void cxr2(float2 (&a)[K], bool ctrl)
{
#pragma unroll
    for (int k = 0; k < K; k++)
        if ((k & TM) == 0) {
            float2 u = a[k], v = a[k | TM];
            a[k].x      = ctrl ? v.x : u.x;
            a[k].y      = ctrl ? v.y : u.y;
            a[k | TM].x = ctrl ? u.x : v.x;
            a[k | TM].y = ctrl ? u.y : v.y;
        }
}

template <int K>                // CX, bool ctrl, COMPONENT target (x<->y)
__device__ __forceinline__ void cxc2(float2 (&a)[K], bool ctrl)
{
#pragma unroll
    for (int k = 0; k < K; k++) {
        float x = a[k].x, y = a[k].y;
        a[k].x = ctrl ? y : x;
        a[k].y = ctrl ? x : y;
    }
}

template <int K, int CM, int TM>  // CX, packed ctrl + packed target (rename)
__device__ __forceinline__ void cxrr2(float2 (&a)[K])
{
#pragma unroll
    for (int k = 0; k < K; k++)
        if ((k & CM) && !(k & TM)) {
            float2 t = a[k]; a[k] = a[k | TM]; a[k | TM] = t;
        }
}

template <int K, int TM>        // CX, ctrl = COMPONENT bit, packed target
__device__ __forceinline__ void cxcr2(float2 (&a)[K])
{
#pragma unroll
    for (int k = 0; k < K; k++)
        if ((k & TM) == 0) {    // swap y-components (ctrl=1 amps) across TM
            float t = a[k].y; a[k].y = a[k | TM].y; a[k | TM].y = t;
        }
}

// ---------------------------------------------------------------------------
// edge circuit (r8/r11/r12-verified body).
//   lane bits: m1=w1, m2=w0, m4=w3, m8=w5, m16=w6, m32=w8
//   packed-index bits: m1=w7, m2=w2, m4=w4;  component = w9
// ---------------------------------------------------------------------------
__device__ __forceinline__ void edge_circuit(
    int e, int lane, const float* __restrict__ H,
    const int* __restrict__ snd, const int* __restrict__ rcv,
    const float* __restrict__ cte, const float* __restrict__ ste,
    const float* __restrict__ th_e,
    float* __restrict__ out, float* __restrict__ M, bool do_agg)
{
    const int se = snd[e], re = rcv[e];

    float f[10];
#pragma unroll
    for (int k = 0; k < 5; k++) { f[k] = H[se * 5 + k]; f[5 + k] = H[re * 5 + k]; }

    float cw[10], sw[10];
#pragma unroll
    for (int w = 0; w < 10; w++) {
        float h = 0.5f * (f[w] + th_e[w]);      // absorbed first RY
        sw[w] = __sinf(h);
        cw[w] = __cosf(h);
    }

    float pl = 1.f;
    pl *= (lane & 1)  ? sw[1] : cw[1];
    pl *= (lane & 2)  ? sw[0] : cw[0];
    pl *= (lane & 4)  ? sw[3] : cw[3];
    pl *= (lane & 8)  ? sw[5] : cw[5];
    pl *= (lane & 16) ? sw[6] : cw[6];
    pl *= (lane & 32) ? sw[8] : cw[8];
    float2 a[8];
#pragma unroll
    for (int k = 0; k < 8; k++) {
        float p = pl;
        p *= (k & 1) ? sw[7] : cw[7];
        p *= (k & 2) ? sw[2] : cw[2];
        p *= (k & 4) ? sw[4] : cw[4];
        a[k].x = p * cw[9];
        a[k].y = p * sw[9];
    }

    cxl2<8, 1>(a, (lane & 2) != 0);              // cx(0,1)
    cxr2<8, 2>(a, (lane & 4) != 0);              // cx(3,2)
    cxr2<8, 4>(a, (lane & 8) != 0);              // cx(5,4)
    cxr2<8, 1>(a, (lane & 16) != 0);             // cx(6,7)
    cxc2<8>(a, (lane & 32) != 0);                // cx(8,9)
    ryl2<8, 1>(a, lane, cte[10], ste[10]);       // ry(10,w1)
    ryr2<8, 2>(a, cte[11], ste[11]);             // ry(11,w2)
    cxr2<8, 2>(a, (lane & 1) != 0);              // cx(1,2)
    ryr2<8, 1>(a, cte[12], ste[12]);             // ry(12,w7)
    ryc2<8>(a, cte[13], ste[13]);                // ry(13,w9)
    cxcr2<8, 1>(a);                              // cx(9,7)
    ryr2<8, 2>(a, cte[14], ste[14]);             // ry(14,w2)
    ryr2<8, 4>(a, cte[15], ste[15]);             // ry(15,w4)
    cxrr2<8, 2, 4>(a);                           // cx(2,4)
    ryr2<8, 4>(a, cte[16], ste[16]);             // ry(16,w4)
    ryr2<8, 1>(a, cte[17], ste[17]);             // ry(17,w7)
    cxrr2<8, 4, 1>(a);                           // cx(4,7)
    ryr2<8, 1>(a, cte[18], ste[18]);             // ry(18,w7)

    float z = 0.f;
#pragma unroll
    for (int k = 0; k < 8; k++) {
        float v = a[k].x * a[k].x + a[k].y * a[k].y;
        z += (k & 1) ? -v : v;
    }
#pragma unroll
    for (int o = 32; o > 0; o >>= 1) z += __shfl_xor(z, o, 64);
    float ev = 0.5f * (1.f - z);

    if (lane == 0) out[e] = ev;
    if (do_agg) {
        if (lane < 5)       atomicAdd(&M[re * 10 + lane], ev * f[lane]);
        else if (lane < 10) atomicAdd(&M[se * 10 + lane], ev * f[lane]);
    }
}

// ---------------------------------------------------------------------------
// node circuit (r12-verified 12-qubit body). Per-lane redundant trig,
// no LDS, no syncthreads; M buffers are single-use (double-buffered).
//   packed m1,2,4,8,16 = {w10,w5,w2,w13,w3}; comp = w14
//   lane m1..m32 = {w7,w1,w0,w6,w4,w11}
// ---------------------------------------------------------------------------
__device__ __forceinline__ void node_circuit(
    int n, int lane, const float* __restrict__ H, const float* __restrict__ M,
    const float* __restrict__ ctn, const float* __restrict__ stn,
    const float* __restrict__ th_n,
    const float* __restrict__ X, float* __restrict__ Hout)
{
    float cw[12], sw[12];
    const int wire_of_pb[12] = {10, 5, 2, 13, 3, 14, 7, 1, 0, 6, 4, 11};
#pragma unroll
    for (int pb = 0; pb < 12; pb++) {
        int w_ = wire_of_pb[pb];
        float ang = ((w_ < 10) ? M[n * 10 + w_] : H[n * 5 + (w_ - 10)]) + th_n[w_];
        float h = 0.5f * ang;                   // absorbed first RY
        sw[pb] = __sinf(h);
        cw[pb] = __cosf(h);
    }

    // merged-gate trig (r11/r12-verified values)
    float h1721 = 0.5f * (th_n[17] + th_n[21]);
    float h1822 = 0.5f * (th_n[18] + th_n[22]);
    float h1928 = 0.5f * (th_n[19] + th_n[28]);
    float h2326 = 0.5f * (th_n[23] + th_n[26]);
    float h2427 = 0.5f * (th_n[24] + th_n[27]);
    float ms1721 = __sinf(h1721), mc1721 = __cosf(h1721);
    float ms1822 = __sinf(h1822), mc1822 = __cosf(h1822);
    float ms1928 = __sinf(h1928), mc1928 = __cosf(h1928);
    float ms2326 = __sinf(h2326), mc2326 = __cosf(h2326);
    float ms2427 = __sinf(h2427), mc2427 = __cosf(h2427);

    // product state: lane bits pb6..11 = {w7,w1,w0,w6,w4,w11},
    // packed pb0..4 = {w10,w5,w2,w13,w3}, comp pb5 = w14
    float pw = 1.f;
    pw *= (lane & 1)  ? sw[6]  : cw[6];
    pw *= (lane & 2)  ? sw[7]  : cw[7];
    pw *= (lane & 4)  ? sw[8]  : cw[8];
    pw *= (lane & 8)  ? sw[9]  : cw[9];
    pw *= (lane & 16) ? sw[10] : cw[10];
    pw *= (lane & 32) ? sw[11] : cw[11];
    float2 a[32];
#pragma unroll
    for (int k = 0; k < 32; k++) {
        float p = pw;
        p *= (k & 1)  ? sw[0] : cw[0];
        p *= (k & 2)  ? sw[1] : cw[1];
        p *= (k & 4)  ? sw[2] : cw[2];
        p *= (k & 8)  ? sw[3] : cw[3];
        p *= (k & 16) ? sw[4] : cw[4];
        a[k].x = p * cw[5];                     // component = w14
        a[k].y = p * sw[5];
    }

    cxl2<32, 2>(a, (lane & 4) != 0);             // cx(0,1)   tgt w1 (DPP)
    cxrr2<32, 16, 4>(a);                         // cx(3,2)   ctrl w3 pk-m16
    cxr2<32, 2>(a, (lane & 16) != 0);            // cx(4,5)   ctrl w4 m16
    cxl2<32, 8>(a, (lane & 1) != 0);             // cx(7,6)   ctrl w7 m1
    cxr2<32, 1>(a, (lane & 32) != 0);            // cx(11,10) ctrl w11 m32
    ryl2<32, 2>(a, lane, ctn[15], stn[15]);      // ry(15,w1) (DPP)
    ryr2<32, 4>(a, ctn[16], stn[16]);            // ry(16,w2)
    cxr2<32, 4>(a, (lane & 2) != 0);             // cx(1,2)
    ryr2<32, 2>(a, ctn[14], stn[14]);            // ry(14,w5)
    ryl2<32, 8>(a, lane, ctn[15], stn[15]);      // ry(15,w6) (DPP)
    cxr2<32, 2>(a, (lane & 8) != 0);             // cx(6,5)
    ryr2<32, 1>(a, mc1721, ms1721);              // ry(17+21,w10)
    ryr2<32, 8>(a, mc1822, ms1822);              // ry(18+22,w13)
    ryc2<32>(a, mc1928, ms1928);                 // ry(19+28,w14)
    ryr2<32, 4>(a, ctn[19], stn[19]);            // ry(19,w2)
    ryr2<32, 2>(a, ctn[20], stn[20]);            // ry(20,w5)
    cxrr2<32, 4, 2>(a);                          // cx(2,5)
    cxrr2<32, 8, 1>(a);                          // cx(13,10)
    ryr2<32, 2>(a, mc2326, ms2326);              // ry(23+26,w5)
    ryr2<32, 1>(a, mc2427, ms2427);              // ry(24+27,w10)
    ryl2<32, 4>(a, lane, ctn[25], stn[25]);      // ry(25,w0) shfl
    cxr2<32, 2>(a, (lane & 4) != 0);             // cx(0,5)
    cxcr2<32, 1>(a);                             // cx(14,10)
    ryr2<32, 2>(a, ctn[29], stn[29]);            // ry(29,w5)
    ryr2<32, 1>(a, ctn[30], stn[30]);            // ry(30,w10)

    // expz: wire5 -> packed m2, wire10 -> packed m1
    float z5 = 0.f, z10 = 0.f;
#pragma unroll
    for (int k = 0; k < 32; k++) {
        float v = a[k].x * a[k].x + a[k].y * a[k].y;
        z5  += (k & 2) ? -v : v;
        z10 += (k & 1) ? -v : v;
    }
#pragma unroll
    for (int o = 32; o > 0; o >>= 1) {
        z5  += __shfl_xor(z5, o, 64);
        z10 += __shfl_xor(z10, o, 64);
    }
    if (lane == 0) {
        const float PI_ = 3.14159265358979323846f;
        Hout[n * 5 + 0] = PI_ * (1.f - z5);
        Hout[n * 5 + 1] = PI_ * (1.f - z10);
        Hout[n * 5 + 2] = X[n * 3 + 0];
        Hout[n * 5 + 3] = X[n * 3 + 1];
        Hout[n * 5 + 4] = X[n * 3 + 2];
    }
}

// ---------------------------------------------------------------------------
// shared prep body (device function): decode, H0, trig tables, zero Ma+Mb
// ---------------------------------------------------------------------------
__device__ __forceinline__ void prep_body(
    int gtid, int nthreads,
    const float* __restrict__ X, const float* __restrict__ Ri,
    const float* __restrict__ Ro, const float* __restrict__ W,
    const float* __restrict__ th_e, const float* __restrict__ th_n,
    int* __restrict__ snd, int* __restrict__ rcv, float* __restrict__ H0,
    float* __restrict__ cte, float* __restrict__ ste,
    float* __restrict__ ctn, float* __restrict__ stn,
    float* __restrict__ Ma, float* __restrict__ Mb)
{
    for (int idx = gtid; idx < N_NODES * N_EDGES; idx += nthreads) {
        int n = idx / N_EDGES, e = idx - n * N_EDGES;
        if (Ro[idx] > 0.5f) snd[e] = n;
        if (Ri[idx] > 0.5f) rcv[e] = n;
    }
    if (gtid < N_NODES) {
        int n = gtid;
        float x0 = X[n * 3 + 0], x1 = X[n * 3 + 1], x2 = X[n * 3 + 2];
        float t0 = x0 * W[0] + x1 * W[2] + x2 * W[4];
        float t1 = x0 * W[1] + x1 * W[3] + x2 * W[5];
        const float TP = 6.2831853071795864769f;
        H0[n * 5 + 0] = TP / (1.f + __expf(-t0));
        H0[n * 5 + 1] = TP / (1.f + __expf(-t1));
        H0[n * 5 + 2] = x0;
        H0[n * 5 + 3] = x1;
        H0[n * 5 + 4] = x2;
    } else if (gtid >= 512 && gtid < 512 + 19) {
        int j = gtid - 512;
        float h = 0.5f * th_e[j];
        cte[j] = __cosf(h); ste[j] = __sinf(h);
    } else if (gtid >= 576 && gtid < 576 + 31) {
        int j = gtid - 576;
        float h = 0.5f * th_n[j];
        ctn[j] = __cosf(h); stn[j] = __sinf(h);
    } else if (gtid >= 1024 && gtid < 1024 + N_NODES * 10) {
        Ma[gtid - 1024] = 0.f;
    } else if (gtid >= 5120 && gtid < 5120 + N_NODES * 10) {
        Mb[gtid - 5120] = 0.f;
    }
}

// ---------------------------------------------------------------------------
// MEGAKERNEL (cooperative): prep -> E1 -> N1 -> E2 -> N2 -> E3, grid-stride.
// __launch_bounds__(256, 2): VGPR <= 256 -> >=2 blocks/CU -> capacity >= 512.
// ---------------------------------------------------------------------------
__global__ __launch_bounds__(256, 2) void mega_kernel(
    const float* __restrict__ X, const float* __restrict__ Ri,
    const float* __restrict__ Ro, const float* __restrict__ W,
    const float* __restrict__ th_e, const float* __restrict__ th_n,
    int* __restrict__ snd, int* __restrict__ rcv,
    float* __restrict__ Ha, float* __restrict__ Hb,
    float* __restrict__ cte, float* __restrict__ ste,
    float* __restrict__ ctn, float* __restrict__ stn,
    float* __restrict__ Ma, float* __restrict__ Mb,
    float* __restrict__ ev, float* __restrict__ out)
{
    cg::grid_group grid = cg::this_grid();
    const int nthreads = gridDim.x * 256;
    const int nwaves   = gridDim.x * 4;
    const int gtid = blockIdx.x * 256 + threadIdx.x;
    const int wid  = gtid >> 6;
    const int lane = gtid & 63;

    prep_body(gtid, nthreads, X, Ri, Ro, W, th_e, th_n,
              snd, rcv, Ha, cte, ste, ctn, stn, Ma, Mb);
    grid.sync();

    for (int e = wid; e < N_EDGES; e += nwaves)
        edge_circuit(e, lane, Ha, snd, rcv, cte, ste, th_e, ev, Ma, true);
    grid.sync();

    for (int n = wid; n < N_NODES; n += nwaves)
        node_circuit(n, lane, Ha, Ma, ctn, stn, th_n, X, Hb);
    grid.sync();

    for (int e = wid; e < N_EDGES; e += nwaves)
        edge_circuit(e, lane, Hb, snd, rcv, cte, ste, th_e, ev, Mb, true);
    grid.sync();

    for (int n = wid; n < N_NODES; n += nwaves)
        node_circuit(n, lane, Hb, Mb, ctn, stn, th_n, X, Ha);
    grid.sync();

    for (int e = wid; e < N_EDGES; e += nwaves)
        edge_circuit(e, lane, Ha, snd, rcv, cte, ste, th_e, out, Ma, false);
}

// ---------------------------------------------------------------------------
// FALLBACK kernels (r12-equivalent multi-dispatch path, M double-buffered)
// ---------------------------------------------------------------------------
__global__ __launch_bounds__(256) void prep_kernel(
    const float* __restrict__ X, const float* __restrict__ Ri,
    const float* __restrict__ Ro, const float* __restrict__ W,
    const float* __restrict__ th_e, const float* __restrict__ th_n,
    int* __restrict__ snd, int* __restrict__ rcv, float* __restrict__ H0,
    float* __restrict__ cte, float* __restrict__ ste,
    float* __restrict__ ctn, float* __restrict__ stn,
    float* __restrict__ Ma, float* __restrict__ Mb)
{
    int gtid = blockIdx.x * blockDim.x + threadIdx.x;
    prep_body(gtid, (int)(gridDim.x * blockDim.x), X, Ri, Ro, W, th_e, th_n,
              snd, rcv, H0, cte, ste, ctn, stn, Ma, Mb);
}

__global__ __launch_bounds__(256) void edge_kernel(
    const float* __restrict__ H, const int* __restrict__ snd, const int* __restrict__ rcv,
    const float* __restrict__ cte, const float* __restrict__ ste,
    const float* __restrict__ th_e,
    float* __restrict__ out, float* __restrict__ M, int do_agg)
{
    const int e = blockIdx.x * 4 + (threadIdx.x >> 6);
    const int lane = threadIdx.x & 63;
    edge_circuit(e, lane, H, snd, rcv, cte, ste, th_e, out, M, do_agg != 0);
}

__global__ __launch_bounds__(256) void node_kernel(
    const float* __restrict__ H, const float* __restrict__ M,
    const float* __restrict__ ctn, const float* __restrict__ stn,
    const float* __restrict__ th_n,
    const float* __restrict__ X, float* __restrict__ Hout)
{
    const int n = blockIdx.x * 4 + (threadIdx.x >> 6);
    const int lane = threadIdx.x & 63;
    node_circuit(n, lane, H, M, ctn, stn, th_n, X, Hout);
}

// ---------------------------------------------------------------------------
extern "C" void kernel_launch(void* const* d_in, const int* in_sizes, int n_in,
                              void* d_out, int out_size, void* d_ws, size_t ws_size,
                              hipStream_t stream)
{
    const float* X    = (const float*)d_in[0];
    const float* Ri   = (const float*)d_in[1];
    const float* Ro   = (const float*)d_in[2];
    const float* W    = (const float*)d_in[3];
    const float* th_e = (const float*)d_in[4];
    const float* th_n = (const float*)d_in[5];
    float* out = (float*)d_out;

    float* Ha  = (float*)d_ws;              // 1920
    float* Hb  = Ha + N_NODES * 5;          // 1920
    float* ev  = Hb + N_NODES * 5;          // 1280
    int*   snd = (int*)(ev + N_EDGES);      // 1280
    int*   rcv = snd + N_EDGES;             // 1280
    float* Ma  = (float*)(rcv + N_EDGES);   // 3840
    float* Mb  = Ma + N_NODES * 10;         // 3840
    float* cte = Mb + N_NODES * 10;         // 19
    float* ste = cte + 19;                  // 19
    float* ctn = ste + 19;                  // 31
    float* stn = ctn + 31;                  // 31

    // size cooperative grid from occupancy (pure query, capture-safe)
    int maxB = 0;
    hipError_t qerr = hipOccupancyMaxActiveBlocksPerMultiprocessor(
        &maxB, (const void*)mega_kernel, 256, 0);
    int grid = NBLOCKS;
    if (qerr == hipSuccess && maxB >= 1) {
        int cap = maxB * 256;               // 256 CUs on MI355X
        if (cap < grid) grid = cap;
    }

    hipError_t lerr = hipErrorUnknown;
    if (qerr == hipSuccess && maxB >= 1 && grid >= 64) {
        void* args[] = {
            (void*)&X, (void*)&Ri, (void*)&Ro, (void*)&W, (void*)&th_e, (void*)&th_n,
            (void*)&snd, (void*)&rcv, (void*)&Ha, (void*)&Hb,
            (void*)&cte, (void*)&ste, (void*)&ctn, (void*)&stn,
            (void*)&Ma, (void*)&Mb, (void*)&ev, (void*)&out
        };
        lerr = hipLaunchCooperativeKernel((const void*)mega_kernel,
                                          dim3(grid), dim3(256), args, 0, stream);
    }

    if (lerr != hipSuccess) {
        // fallback: r12-verified multi-dispatch path (M double-buffered)
        prep_kernel<<<(N_NODES * N_EDGES + 255) / 256, 256, 0, stream>>>(
            X, Ri, Ro, W, th_e, th_n, snd, rcv, Ha, cte, ste, ctn, stn, Ma, Mb);
        edge_kernel<<<N_EDGES / 4, 256, 0, stream>>>(Ha, snd, rcv, cte, ste, th_e, ev, Ma, 1);
        node_kernel<<<N_NODES / 4, 256, 0, stream>>>(Ha, Ma, ctn, stn, th_n, X, Hb);
        edge_kernel<<<N_EDGES / 4, 256, 0, stream>>>(Hb, snd, rcv, cte, ste, th_e, ev, Mb, 1);
        node_kernel<<<N_NODES / 4, 256, 0, stream>>>(Hb, Mb, ctn, stn, th_n, X, Ha);
        edge_kernel<<<N_EDGES / 4, 256, 0, stream>>>(Ha, snd, rcv, cte, ste, th_e, out, Ma, 0);
    }
}

// Round 15
// 51.169 us; speedup vs baseline: 3.0165x; 3.0165x over previous
//
#include <hip/hip_runtime.h>
#include <math.h>

#define N_NODES 384
#define N_EDGES 1280

// ---------------------------------------------------------------------------
// Lane-exchange: DPP for xor masks 1,2,8 (VALU pipe, verified r6-r12):
//   xor1 = quad_perm [1,0,3,2]; xor2 = quad_perm [2,3,0,1]; xor8 = row_ror:8.
// Masks 4,16,32 -> __shfl_xor. Permlane swaps: BANNED (r3/r4 failures).
// Cooperative grid.sync: BANNED (r14: ~30us per sync on 8 XCDs).
// ---------------------------------------------------------------------------
template <int M>
__device__ __forceinline__ float lxor_f(float x)
{
    if constexpr (M == 1) {
        return __builtin_bit_cast(float, __builtin_amdgcn_mov_dpp(
            __builtin_bit_cast(int, x), 0xB1, 0xF, 0xF, true));
    } else if constexpr (M == 2) {
        return __builtin_bit_cast(float, __builtin_amdgcn_mov_dpp(
            __builtin_bit_cast(int, x), 0x4E, 0xF, 0xF, true));
    } else if constexpr (M == 8) {
        return __builtin_bit_cast(float, __builtin_amdgcn_mov_dpp(
            __builtin_bit_cast(int, x), 0x128, 0xF, 0xF, true));
    } else {
        return __shfl_xor(x, M, 64);        // masks 4, 16, 32
    }
}

// ---------------------------------------------------------------------------
// float2-packed gate helpers (r8/r11/r12-verified algebra).
// ---------------------------------------------------------------------------
template <int K, int M>         // RY on a packed-index bit (elementwise f2)
__device__ __forceinline__ void ryr2(float2 (&a)[K], float c_, float s_)
{
#pragma unroll
    for (int k = 0; k < K; k++)
        if ((k & M) == 0) {
            float2 u = a[k], v = a[k | M];
            a[k].x     = c_ * u.x - s_ * v.x;
            a[k].y     = c_ * u.y - s_ * v.y;
            a[k | M].x = s_ * u.x + c_ * v.x;
            a[k | M].y = s_ * u.y + c_ * v.y;
        }
}

template <int K>                // RY on the component bit (x/y rotate)
__device__ __forceinline__ void ryc2(float2 (&a)[K], float c_, float s_)
{
#pragma unroll
    for (int k = 0; k < K; k++) {
        float x = a[k].x, y = a[k].y;
        a[k].x = c_ * x - s_ * y;
        a[k].y = s_ * x + c_ * y;
    }
}

template <int K, int LM>        // RY on a lane bit
__device__ __forceinline__ void ryl2(float2 (&a)[K], int lane, float c_, float s_)
{
    const float ss = (lane & LM) ? s_ : -s_;
#pragma unroll
    for (int k = 0; k < K; k++) {
        float ox = lxor_f<LM>(a[k].x);
        float oy = lxor_f<LM>(a[k].y);
        a[k].x = fmaf(ss, ox, c_ * a[k].x);
        a[k].y = fmaf(ss, oy, c_ * a[k].y);
    }
}

template <int K, int TM>        // CX, bool ctrl, lane-bit target
__device__ __forceinline__ void cxl2(float2 (&a)[K], bool ctrl)
{
#pragma unroll
    for (int k = 0; k < K; k++) {
        float ox = lxor_f<TM>(a[k].x);
        float oy = lxor_f<TM>(a[k].y);
        a[k].x = ctrl ? ox : a[k].x;
        a[k].y = ctrl ? oy : a[k].y;
    }
}

template <int K, int TM>        // CX, bool ctrl, packed-index target
__device__ __forceinline__ void cxr2(float2 (&a)[K], bool ctrl)
{
#pragma unroll
    for (int k = 0; k < K; k++)
        if ((k & TM) == 0) {
            float2 u = a[k], v = a[k | TM];
            a[k].x      = ctrl ? v.x : u.x;
            a[k].y      = ctrl ? v.y : u.y;
            a[k | TM].x = ctrl ? u.x : v.x;
            a[k | TM].y = ctrl ? u.y : v.y;
        }
}

template <int K>                // CX, bool ctrl, COMPONENT target (x<->y)
__device__ __forceinline__ void cxc2(float2 (&a)[K], bool ctrl)
{
#pragma unroll
    for (int k = 0; k < K; k++) {
        float x = a[k].x, y = a[k].y;
        a[k].x = ctrl ? y : x;
        a[k].y = ctrl ? x : y;
    }
}

template <int K, int CM, int TM>  // CX, packed ctrl + packed target (rename)
__device__ __forceinline__ void cxrr2(float2 (&a)[K])
{
#pragma unroll
    for (int k = 0; k < K; k++)
        if ((k & CM) && !(k & TM)) {
            float2 t = a[k]; a[k] = a[k | TM]; a[k | TM] = t;
        }
}

template <int K, int TM>        // CX, ctrl = COMPONENT bit, packed target
__device__ __forceinline__ void cxcr2(float2 (&a)[K])
{
#pragma unroll
    for (int k = 0; k < K; k++)
        if ((k & TM) == 0) {    // swap y-components (ctrl=1 amps) across TM
            float t = a[k].y; a[k].y = a[k | TM].y; a[k | TM].y = t;
        }
}

// ---------------------------------------------------------------------------
// H0 row: [2pi*sig(x.W0), 2pi*sig(x.W1), x0, x1, x2]  (r8-verified math)
// ---------------------------------------------------------------------------
__device__ __forceinline__ void h0_of(int n, const float* __restrict__ X,
                                      const float* __restrict__ W, float (&h)[5])
{
    float x0 = X[n * 3 + 0], x1 = X[n * 3 + 1], x2 = X[n * 3 + 2];
    float t0 = x0 * W[0] + x1 * W[2] + x2 * W[4];
    float t1 = x0 * W[1] + x1 * W[3] + x2 * W[5];
    const float TP = 6.2831853071795864769f;
    h[0] = TP / (1.f + __expf(-t0));
    h[1] = TP / (1.f + __expf(-t1));
    h[2] = x0; h[3] = x1; h[4] = x2;
}

// ---------------------------------------------------------------------------
// edge circuit body (r8/r11/r12-verified): input f[10], gate trig gc/gs for
// th_e[10..18]; returns ev on all lanes.
//   lane bits: m1=w1, m2=w0, m4=w3, m8=w5, m16=w6, m32=w8
//   packed-index bits: m1=w7, m2=w2, m4=w4;  component = w9
// ---------------------------------------------------------------------------
__device__ __forceinline__ float edge_ev(
    int lane, const float (&f)[10], const float* __restrict__ th_e,
    const float (&gc)[9], const float (&gs)[9])
{
    float cw[10], sw[10];
#pragma unroll
    for (int w = 0; w < 10; w++) {
        float h = 0.5f * (f[w] + th_e[w]);      // absorbed first RY
        sw[w] = __sinf(h);
        cw[w] = __cosf(h);
    }

    float pl = 1.f;
    pl *= (lane & 1)  ? sw[1] : cw[1];
    pl *= (lane & 2)  ? sw[0] : cw[0];
    pl *= (lane & 4)  ? sw[3] : cw[3];
    pl *= (lane & 8)  ? sw[5] : cw[5];
    pl *= (lane & 16) ? sw[6] : cw[6];
    pl *= (lane & 32) ? sw[8] : cw[8];
    float2 a[8];
#pragma unroll
    for (int k = 0; k < 8; k++) {
        float p = pl;
        p *= (k & 1) ? sw[7] : cw[7];
        p *= (k & 2) ? sw[2] : cw[2];
        p *= (k & 4) ? sw[4] : cw[4];
        a[k].x = p * cw[9];
        a[k].y = p * sw[9];
    }

    cxl2<8, 1>(a, (lane & 2) != 0);              // cx(0,1)
    cxr2<8, 2>(a, (lane & 4) != 0);              // cx(3,2)
    cxr2<8, 4>(a, (lane & 8) != 0);              // cx(5,4)
    cxr2<8, 1>(a, (lane & 16) != 0);             // cx(6,7)
    cxc2<8>(a, (lane & 32) != 0);                // cx(8,9)
    ryl2<8, 1>(a, lane, gc[0], gs[0]);           // ry(10,w1)
    ryr2<8, 2>(a, gc[1], gs[1]);                 // ry(11,w2)
    cxr2<8, 2>(a, (lane & 1) != 0);              // cx(1,2)
    ryr2<8, 1>(a, gc[2], gs[2]);                 // ry(12,w7)
    ryc2<8>(a, gc[3], gs[3]);                    // ry(13,w9)
    cxcr2<8, 1>(a);                              // cx(9,7)
    ryr2<8, 2>(a, gc[4], gs[4]);                 // ry(14,w2)
    ryr2<8, 4>(a, gc[5], gs[5]);                 // ry(15,w4)
    cxrr2<8, 2, 4>(a);                           // cx(2,4)
    ryr2<8, 4>(a, gc[6], gs[6]);                 // ry(16,w4)
    ryr2<8, 1>(a, gc[7], gs[7]);                 // ry(17,w7)
    cxrr2<8, 4, 1>(a);                           // cx(4,7)
    ryr2<8, 1>(a, gc[8], gs[8]);                 // ry(18,w7)

    float z = 0.f;
#pragma unroll
    for (int k = 0; k < 8; k++) {
        float v = a[k].x * a[k].x + a[k].y * a[k].y;
        z += (k & 1) ? -v : v;
    }
#pragma unroll
    for (int o = 32; o > 0; o >>= 1) z += __shfl_xor(z, o, 64);
    return 0.5f * (1.f - z);
}

// ---------------------------------------------------------------------------
// edge kernel, 4 edges/block (4 waves).
// MODE 0: decode snd/rcv inline (one-hot column scan) + H0 inline; write
//         snd/rcv + EW.   MODE 1: read snd/rcv + H buffer; write EW.
// MODE 2: read snd/rcv + H buffer; write final out only.
// EW[e*10+k] = ev*f[k]: k<5 -> mi contribution to rcv[e]; k>=5 -> mo to snd[e].
// ---------------------------------------------------------------------------
template <int MODE>
__global__ __launch_bounds__(256) void edge_kernel(
    const float* __restrict__ H,
    const float* __restrict__ X, const float* __restrict__ W,
    const float* __restrict__ Ri, const float* __restrict__ Ro,
    int* __restrict__ snd, int* __restrict__ rcv,
    const float* __restrict__ th_e,
    float* __restrict__ EW, float* __restrict__ out)
{
    const int e = blockIdx.x * 4 + (threadIdx.x >> 6);
    const int lane = threadIdx.x & 63;

    int se, re;
    if constexpr (MODE == 0) {
        int s_ = 0, r_ = 0;
#pragma unroll
        for (int k = 0; k < 6; k++) {
            int n = lane + 64 * k;
            if (Ro[n * N_EDGES + e] > 0.5f) s_ = n;
            if (Ri[n * N_EDGES + e] > 0.5f) r_ = n;
        }
#pragma unroll
        for (int o = 32; o > 0; o >>= 1) {
            s_ = max(s_, __shfl_xor(s_, o, 64));
            r_ = max(r_, __shfl_xor(r_, o, 64));
        }
        se = s_; re = r_;
        if (lane == 0) { snd[e] = se; rcv[e] = re; }
    } else {
        se = snd[e]; re = rcv[e];
    }

    float f[10];
    if constexpr (MODE == 0) {
        float hs[5], hr[5];
        h0_of(se, X, W, hs);
        h0_of(re, X, W, hr);
#pragma unroll
        for (int k = 0; k < 5; k++) { f[k] = hs[k]; f[5 + k] = hr[k]; }
    } else {
#pragma unroll
        for (int k = 0; k < 5; k++) { f[k] = H[se * 5 + k]; f[5 + k] = H[re * 5 + k]; }
    }

    float gc[9], gs[9];                          // gate trig th_e[10..18]
#pragma unroll
    for (int j = 0; j < 9; j++) {
        float h = 0.5f * th_e[10 + j];
        gs[j] = __sinf(h); gc[j] = __cosf(h);
    }

    float ev = edge_ev(lane, f, th_e, gc, gs);

    if constexpr (MODE == 2) {
        if (lane == 0) out[e] = ev;
    } else {
        if (lane < 10) EW[e * 10 + lane] = ev * f[lane];
    }
}

// ---------------------------------------------------------------------------
// node kernel, 4 nodes/block (4 waves). 12-qubit circuit (r12-verified).
// Gather-reduce replaces atomics: lane scans 20 edges, accumulates EW rows
// matching its node, then 10-float butterfly reduce.
// FIRST=1: H values computed inline from X,W (input H == H0).
//   packed m1,2,4,8,16 = {w10,w5,w2,w13,w3}; comp = w14
//   lane m1..m32 = {w7,w1,w0,w6,w4,w11}
// ---------------------------------------------------------------------------
template <int FIRST>
__global__ __launch_bounds__(256) void node_kernel(
    const float* __restrict__ H,
    const float* __restrict__ X, const float* __restrict__ W,
    const int* __restrict__ snd, const int* __restrict__ rcv,
    const float* __restrict__ EW,
    const float* __restrict__ th_n, float* __restrict__ Hout)
{
    const int n = blockIdx.x * 4 + (threadIdx.x >> 6);
    const int lane = threadIdx.x & 63;

    // gather incident-edge contributions
    float mi[5] = {0.f, 0.f, 0.f, 0.f, 0.f};
    float mo[5] = {0.f, 0.f, 0.f, 0.f, 0.f};
#pragma unroll
    for (int c = 0; c < N_EDGES / 64; c++) {
        int e = lane + c * 64;
        int se = snd[e], re = rcv[e];
        if (re == n) {
#pragma unroll
            for (int k = 0; k < 5; k++) mi[k] += EW[e * 10 + k];
        }
        if (se == n) {
#pragma unroll
            for (int k = 0; k < 5; k++) mo[k] += EW[e * 10 + 5 + k];
        }
    }
#pragma unroll
    for (int o = 32; o > 0; o >>= 1) {
#pragma unroll
        for (int k = 0; k < 5; k++) {
            mi[k] += __shfl_xor(mi[k], o, 64);
            mo[k] += __shfl_xor(mo[k], o, 64);
        }
    }

    // H values for wires 10-14
    float hv[5];
    if constexpr (FIRST) {
        h0_of(n, X, W, hv);
    } else {
#pragma unroll
        for (int k = 0; k < 5; k++) hv[k] = H[n * 5 + k];
    }

    // absorbed-RY base angles per PHYSICAL bit (wire_of_pb = {10,5,2,13,3,14,7,1,0,6,4,11})
    float cw[12], sw[12];
    {
        const float base[12] = {hv[0], mo[0], mi[2], hv[3], mi[3], hv[4],
                                mo[2], mi[1], mi[0], mo[1], mi[4], hv[1]};
        const int thw[12] = {10, 5, 2, 13, 3, 14, 7, 1, 0, 6, 4, 11};
#pragma unroll
        for (int pb = 0; pb < 12; pb++) {
            float h = 0.5f * (base[pb] + th_n[thw[pb]]);
            sw[pb] = __sinf(h);
            cw[pb] = __cosf(h);
        }
    }

    // gate trig (r11/r12-verified angles, incl. merged sums)
    float h_;
    h_ = 0.5f * th_n[15];                float gs15 = __sinf(h_), gc15 = __cosf(h_);
    h_ = 0.5f * th_n[16];                float gs16 = __sinf(h_), gc16 = __cosf(h_);
    h_ = 0.5f * th_n[14];                float gs14 = __sinf(h_), gc14 = __cosf(h_);
    h_ = 0.5f * th_n[19];                float gs19 = __sinf(h_), gc19 = __cosf(h_);
    h_ = 0.5f * th_n[20];                float gs20 = __sinf(h_), gc20 = __cosf(h_);
    h_ = 0.5f * th_n[25];                float gs25 = __sinf(h_), gc25 = __cosf(h_);
    h_ = 0.5f * th_n[29];                float gs29 = __sinf(h_), gc29 = __cosf(h_);
    h_ = 0.5f * th_n[30];                float gs30 = __sinf(h_), gc30 = __cosf(h_);
    h_ = 0.5f * (th_n[17] + th_n[21]);   float ms1721 = __sinf(h_), mc1721 = __cosf(h_);
    h_ = 0.5f * (th_n[18] + th_n[22]);   float ms1822 = __sinf(h_), mc1822 = __cosf(h_);
    h_ = 0.5f * (th_n[19] + th_n[28]);   float ms1928 = __sinf(h_), mc1928 = __cosf(h_);
    h_ = 0.5f * (th_n[23] + th_n[26]);   float ms2326 = __sinf(h_), mc2326 = __cosf(h_);
    h_ = 0.5f * (th_n[24] + th_n[27]);   float ms2427 = __sinf(h_), mc2427 = __cosf(h_);

    // product state: lane bits pb6..11 = {w7,w1,w0,w6,w4,w11},
    // packed pb0..4 = {w10,w5,w2,w13,w3}, comp pb5 = w14
    float pw = 1.f;
    pw *= (lane & 1)  ? sw[6]  : cw[6];
    pw *= (lane & 2)  ? sw[7]  : cw[7];
    pw *= (lane & 4)  ? sw[8]  : cw[8];
    pw *= (lane & 8)  ? sw[9]  : cw[9];
    pw *= (lane & 16) ? sw[10] : cw[10];
    pw *= (lane & 32) ? sw[11] : cw[11];
    float2 a[32];
#pragma unroll
    for (int k = 0; k < 32; k++) {
        float p = pw;
        p *= (k & 1)  ? sw[0] : cw[0];
        p *= (k & 2)  ? sw[1] : cw[1];
        p *= (k & 4)  ? sw[2] : cw[2];
        p *= (k & 8)  ? sw[3] : cw[3];
        p *= (k & 16) ? sw[4] : cw[4];
        a[k].x = p * cw[5];                     // component = w14
        a[k].y = p * sw[5];
    }

    cxl2<32, 2>(a, (lane & 4) != 0);             // cx(0,1)   tgt w1 (DPP)
    cxrr2<32, 16, 4>(a);                         // cx(3,2)   ctrl w3 pk-m16
    cxr2<32, 2>(a, (lane & 16) != 0);            // cx(4,5)   ctrl w4 m16
    cxl2<32, 8>(a, (lane & 1) != 0);             // cx(7,6)   ctrl w7 m1
    cxr2<32, 1>(a, (lane & 32) != 0);            // cx(11,10) ctrl w11 m32
    ryl2<32, 2>(a, lane, gc15, gs15);            // ry(15,w1) (DPP)
    ryr2<32, 4>(a, gc16, gs16);                  // ry(16,w2)
    cxr2<32, 4>(a, (lane & 2) != 0);             // cx(1,2)
    ryr2<32, 2>(a, gc14, gs14);                  // ry(14,w5)
    ryl2<32, 8>(a, lane, gc15, gs15);            // ry(15,w6) (DPP)
    cxr2<32, 2>(a, (lane & 8) != 0);             // cx(6,5)
    ryr2<32, 1>(a, mc1721, ms1721);              // ry(17+21,w10)
    ryr2<32, 8>(a, mc1822, ms1822);              // ry(18+22,w13)
    ryc2<32>(a, mc1928, ms1928);                 // ry(19+28,w14)
    ryr2<32, 4>(a, gc19, gs19);                  // ry(19,w2)
    ryr2<32, 2>(a, gc20, gs20);                  // ry(20,w5)
    cxrr2<32, 4, 2>(a);                          // cx(2,5)
    cxrr2<32, 8, 1>(a);                          // cx(13,10)
    ryr2<32, 2>(a, mc2326, ms2326);              // ry(23+26,w5)
    ryr2<32, 1>(a, mc2427, ms2427);              // ry(24+27,w10)
    ryl2<32, 4>(a, lane, gc25, gs25);            // ry(25,w0) shfl
    cxr2<32, 2>(a, (lane & 4) != 0);             // cx(0,5)
    cxcr2<32, 1>(a);                             // cx(14,10)
    ryr2<32, 2>(a, gc29, gs29);                  // ry(29,w5)
    ryr2<32, 1>(a, gc30, gs30);                  // ry(30,w10)

    // expz: wire5 -> packed m2, wire10 -> packed m1
    float z5 = 0.f, z10 = 0.f;
#pragma unroll
    for (int k = 0; k < 32; k++) {
        float v = a[k].x * a[k].x + a[k].y * a[k].y;
        z5  += (k & 2) ? -v : v;
        z10 += (k & 1) ? -v : v;
    }
#pragma unroll
    for (int o = 32; o > 0; o >>= 1) {
        z5  += __shfl_xor(z5, o, 64);
        z10 += __shfl_xor(z10, o, 64);
    }
    if (lane == 0) {
        const float PI_ = 3.14159265358979323846f;
        Hout[n * 5 + 0] = PI_ * (1.f - z5);
        Hout[n * 5 + 1] = PI_ * (1.f - z10);
        Hout[n * 5 + 2] = X[n * 3 + 0];
        Hout[n * 5 + 3] = X[n * 3 + 1];
        Hout[n * 5 + 4] = X[n * 3 + 2];
    }
}

// ---------------------------------------------------------------------------
extern "C" void kernel_launch(void* const* d_in, const int* in_sizes, int n_in,
                              void* d_out, int out_size, void* d_ws, size_t ws_size,
                              hipStream_t stream)
{
    const float* X    = (const float*)d_in[0];
    const float* Ri   = (const float*)d_in[1];
    const float* Ro   = (const float*)d_in[2];
    const float* W    = (const float*)d_in[3];
    const float* th_e = (const float*)d_in[4];
    const float* th_n = (const float*)d_in[5];
    float* out = (float*)d_out;

    int*   snd = (int*)d_ws;                // 1280
    int*   rcv = snd + N_EDGES;             // 1280
    float* EW  = (float*)(rcv + N_EDGES);   // 12800
    float* Hb  = EW + N_EDGES * 10;         // 1920
    float* Ha2 = Hb + N_NODES * 5;          // 1920

    // E1: decode + inline H0 + circuit -> EW
    edge_kernel<0><<<N_EDGES / 4, 256, 0, stream>>>(
        nullptr, X, W, Ri, Ro, snd, rcv, th_e, EW, nullptr);
    // N1: inline H0 + gather EW -> Hb
    node_kernel<1><<<N_NODES / 4, 256, 0, stream>>>(
        nullptr, X, W, snd, rcv, EW, th_n, Hb);
    // E2: Hb -> EW
    edge_kernel<1><<<N_EDGES / 4, 256, 0, stream>>>(
        Hb, X, W, Ri, Ro, snd, rcv, th_e, EW, nullptr);
    // N2: Hb + gather EW -> Ha2
    node_kernel<0><<<N_NODES / 4, 256, 0, stream>>>(
        Hb, X, W, snd, rcv, EW, th_n, Ha2);
    // E3: Ha2 -> out (final)
    edge_kernel<2><<<N_EDGES / 4, 256, 0, stream>>>(
        Ha2, X, W, Ri, Ro, snd, rcv, th_e, nullptr, out);
}

// Round 16
// 50.259 us; speedup vs baseline: 3.0711x; 1.0181x over previous
//
#include <hip/hip_runtime.h>
#include <math.h>

#define N_NODES 384
#define N_EDGES 1280

// ---------------------------------------------------------------------------
// Lane-exchange: DPP for xor masks 1,2,8 (VALU pipe, verified r6-r12):
//   xor1 = quad_perm [1,0,3,2]; xor2 = quad_perm [2,3,0,1]; xor8 = row_ror:8.
// Masks 4,16,32 -> __shfl_xor. Permlane swaps: BANNED (r3/r4 failures).
// Cooperative grid.sync: BANNED (r14: ~30us per sync).
// ---------------------------------------------------------------------------
template <int M>
__device__ __forceinline__ float lxor_f(float x)
{
    if constexpr (M == 1) {
        return __builtin_bit_cast(float, __builtin_amdgcn_mov_dpp(
            __builtin_bit_cast(int, x), 0xB1, 0xF, 0xF, true));
    } else if constexpr (M == 2) {
        return __builtin_bit_cast(float, __builtin_amdgcn_mov_dpp(
            __builtin_bit_cast(int, x), 0x4E, 0xF, 0xF, true));
    } else if constexpr (M == 8) {
        return __builtin_bit_cast(float, __builtin_amdgcn_mov_dpp(
            __builtin_bit_cast(int, x), 0x128, 0xF, 0xF, true));
    } else {
        return __shfl_xor(x, M, 64);        // masks 4, 16, 32
    }
}

// ---------------------------------------------------------------------------
// float2-packed gate helpers (r8/r11/r12-verified algebra).
// ---------------------------------------------------------------------------
template <int K, int M>         // RY on a packed-index bit (elementwise f2)
__device__ __forceinline__ void ryr2(float2 (&a)[K], float c_, float s_)
{
#pragma unroll
    for (int k = 0; k < K; k++)
        if ((k & M) == 0) {
            float2 u = a[k], v = a[k | M];
            a[k].x     = c_ * u.x - s_ * v.x;
            a[k].y     = c_ * u.y - s_ * v.y;
            a[k | M].x = s_ * u.x + c_ * v.x;
            a[k | M].y = s_ * u.y + c_ * v.y;
        }
}

template <int K>                // RY on the component bit (x/y rotate)
__device__ __forceinline__ void ryc2(float2 (&a)[K], float c_, float s_)
{
#pragma unroll
    for (int k = 0; k < K; k++) {
        float x = a[k].x, y = a[k].y;
        a[k].x = c_ * x - s_ * y;
        a[k].y = s_ * x + c_ * y;
    }
}

template <int K, int LM>        // RY on a lane bit
__device__ __forceinline__ void ryl2(float2 (&a)[K], int lane, float c_, float s_)
{
    const float ss = (lane & LM) ? s_ : -s_;
#pragma unroll
    for (int k = 0; k < K; k++) {
        float ox = lxor_f<LM>(a[k].x);
        float oy = lxor_f<LM>(a[k].y);
        a[k].x = fmaf(ss, ox, c_ * a[k].x);
        a[k].y = fmaf(ss, oy, c_ * a[k].y);
    }
}

template <int K, int TM>        // CX, bool ctrl, lane-bit target
__device__ __forceinline__ void cxl2(float2 (&a)[K], bool ctrl)
{
#pragma unroll
    for (int k = 0; k < K; k++) {
        float ox = lxor_f<TM>(a[k].x);
        float oy = lxor_f<TM>(a[k].y);
        a[k].x = ctrl ? ox : a[k].x;
        a[k].y = ctrl ? oy : a[k].y;
    }
}

template <int K, int TM>        // CX, bool ctrl, packed-index target
__device__ __forceinline__ void cxr2(float2 (&a)[K], bool ctrl)
{
#pragma unroll
    for (int k = 0; k < K; k++)
        if ((k & TM) == 0) {
            float2 u = a[k], v = a[k | TM];
            a[k].x      = ctrl ? v.x : u.x;
            a[k].y      = ctrl ? v.y : u.y;
            a[k | TM].x = ctrl ? u.x : v.x;
            a[k | TM].y = ctrl ? u.y : v.y;
        }
}

template <int K>                // CX, bool ctrl, COMPONENT target (x<->y)
__device__ __forceinline__ void cxc2(float2 (&a)[K], bool ctrl)
{
#pragma unroll
    for (int k = 0; k < K; k++) {
        float x = a[k].x, y = a[k].y;
        a[k].x = ctrl ? y : x;
        a[k].y = ctrl ? x : y;
    }
}

template <int K, int CM, int TM>  // CX, packed ctrl + packed target (rename)
__device__ __forceinline__ void cxrr2(float2 (&a)[K])
{
#pragma unroll
    for (int k = 0; k < K; k++)
        if ((k & CM) && !(k & TM)) {
            float2 t = a[k]; a[k] = a[k | TM]; a[k | TM] = t;
        }
}

template <int K, int TM>        // CX, ctrl = COMPONENT bit, packed target
__device__ __forceinline__ void cxcr2(float2 (&a)[K])
{
#pragma unroll
    for (int k = 0; k < K; k++)
        if ((k & TM) == 0) {    // swap y-components (ctrl=1 amps) across TM
            float t = a[k].y; a[k].y = a[k | TM].y; a[k | TM].y = t;
        }
}

// ---------------------------------------------------------------------------
// H0 row: [2pi*sig(x.W0), 2pi*sig(x.W1), x0, x1, x2]  (r8-verified math)
// ---------------------------------------------------------------------------
__device__ __forceinline__ void h0_of(int n, const float* __restrict__ X,
                                      const float* __restrict__ W, float (&h)[5])
{
    float x0 = X[n * 3 + 0], x1 = X[n * 3 + 1], x2 = X[n * 3 + 2];
    float t0 = x0 * W[0] + x1 * W[2] + x2 * W[4];
    float t1 = x0 * W[1] + x1 * W[3] + x2 * W[5];
    const float TP = 6.2831853071795864769f;
    h[0] = TP / (1.f + __expf(-t0));
    h[1] = TP / (1.f + __expf(-t1));
    h[2] = x0; h[3] = x1; h[4] = x2;
}

// ---------------------------------------------------------------------------
// decode kernel: float4-coalesced one-hot scan (r12-prep style, isolated).
// 240 blocks x 256 threads, 2 float4/thread/matrix, one CU round.
// ---------------------------------------------------------------------------
__global__ __launch_bounds__(256) void decode_kernel(
    const float* __restrict__ Ri, const float* __restrict__ Ro,
    int* __restrict__ snd, int* __restrict__ rcv)
{
    const int t = blockIdx.x * 256 + threadIdx.x;     // 61440 threads
    const float4* Ro4 = (const float4*)Ro;
    const float4* Ri4 = (const float4*)Ri;
#pragma unroll
    for (int u = 0; u < 2; u++) {
        int i4 = t * 2 + u;                           // 0..122879
        int n  = (i4 * 4) / N_EDGES;
        int e0 = (i4 * 4) % N_EDGES;                  // 1280 % 4 == 0: row-safe
        float4 ro = Ro4[i4];
        float4 ri = Ri4[i4];
        if (ro.x > 0.5f) snd[e0 + 0] = n;
        if (ro.y > 0.5f) snd[e0 + 1] = n;
        if (ro.z > 0.5f) snd[e0 + 2] = n;
        if (ro.w > 0.5f) snd[e0 + 3] = n;
        if (ri.x > 0.5f) rcv[e0 + 0] = n;
        if (ri.y > 0.5f) rcv[e0 + 1] = n;
        if (ri.z > 0.5f) rcv[e0 + 2] = n;
        if (ri.w > 0.5f) rcv[e0 + 3] = n;
    }
}

// ---------------------------------------------------------------------------
// edge circuit body (r8/r11/r12/r15-verified): input f[10], gate trig gc/gs
// for th_e[10..18]; returns ev on all lanes.
//   lane bits: m1=w1, m2=w0, m4=w3, m8=w5, m16=w6, m32=w8
//   packed-index bits: m1=w7, m2=w2, m4=w4;  component = w9
// ---------------------------------------------------------------------------
__device__ __forceinline__ float edge_ev(
    int lane, const float (&f)[10], const float* __restrict__ th_e,
    const float (&gc)[9], const float (&gs)[9])
{
    float cw[10], sw[10];
#pragma unroll
    for (int w = 0; w < 10; w++) {
        float h = 0.5f * (f[w] + th_e[w]);      // absorbed first RY
        sw[w] = __sinf(h);
        cw[w] = __cosf(h);
    }

    float pl = 1.f;
    pl *= (lane & 1)  ? sw[1] : cw[1];
    pl *= (lane & 2)  ? sw[0] : cw[0];
    pl *= (lane & 4)  ? sw[3] : cw[3];
    pl *= (lane & 8)  ? sw[5] : cw[5];
    pl *= (lane & 16) ? sw[6] : cw[6];
    pl *= (lane & 32) ? sw[8] : cw[8];
    float2 a[8];
#pragma unroll
    for (int k = 0; k < 8; k++) {
        float p = pl;
        p *= (k & 1) ? sw[7] : cw[7];
        p *= (k & 2) ? sw[2] : cw[2];
        p *= (k & 4) ? sw[4] : cw[4];
        a[k].x = p * cw[9];
        a[k].y = p * sw[9];
    }

    cxl2<8, 1>(a, (lane & 2) != 0);              // cx(0,1)
    cxr2<8, 2>(a, (lane & 4) != 0);              // cx(3,2)
    cxr2<8, 4>(a, (lane & 8) != 0);              // cx(5,4)
    cxr2<8, 1>(a, (lane & 16) != 0);             // cx(6,7)
    cxc2<8>(a, (lane & 32) != 0);                // cx(8,9)
    ryl2<8, 1>(a, lane, gc[0], gs[0]);           // ry(10,w1)
    ryr2<8, 2>(a, gc[1], gs[1]);                 // ry(11,w2)
    cxr2<8, 2>(a, (lane & 1) != 0);              // cx(1,2)
    ryr2<8, 1>(a, gc[2], gs[2]);                 // ry(12,w7)
    ryc2<8>(a, gc[3], gs[3]);                    // ry(13,w9)
    cxcr2<8, 1>(a);                              // cx(9,7)
    ryr2<8, 2>(a, gc[4], gs[4]);                 // ry(14,w2)
    ryr2<8, 4>(a, gc[5], gs[5]);                 // ry(15,w4)
    cxrr2<8, 2, 4>(a);                           // cx(2,4)
    ryr2<8, 4>(a, gc[6], gs[6]);                 // ry(16,w4)
    ryr2<8, 1>(a, gc[7], gs[7]);                 // ry(17,w7)
    cxrr2<8, 4, 1>(a);                           // cx(4,7)
    ryr2<8, 1>(a, gc[8], gs[8]);                 // ry(18,w7)

    float z = 0.f;
#pragma unroll
    for (int k = 0; k < 8; k++) {
        float v = a[k].x * a[k].x + a[k].y * a[k].y;
        z += (k & 1) ? -v : v;
    }
#pragma unroll
    for (int o = 32; o > 0; o >>= 1) z += __shfl_xor(z, o, 64);
    return 0.5f * (1.f - z);
}

// ---------------------------------------------------------------------------
// edge kernel, 8 edges/block (8 waves x 64) = 160 blocks, one CU round.
// MODE 0: inline H0 from X,W; write EW.  MODE 1: read H; write EW.
// MODE 2: read H; write final out only.
// EW[e*10+k] = ev*f[k]: k<5 -> mi contribution to rcv[e]; k>=5 -> mo to snd[e].
// ---------------------------------------------------------------------------
template <int MODE>
__global__ __launch_bounds__(512) void edge_kernel(
    const float* __restrict__ H,
    const float* __restrict__ X, const float* __restrict__ W,
    const int* __restrict__ snd, const int* __restrict__ rcv,
    const float* __restrict__ th_e,
    float* __restrict__ EW, float* __restrict__ out)
{
    const int e = blockIdx.x * 8 + (threadIdx.x >> 6);
    const int lane = threadIdx.x & 63;
    const int se = snd[e], re = rcv[e];

    float f[10];
    if constexpr (MODE == 0) {
        float hs[5], hr[5];
        h0_of(se, X, W, hs);
        h0_of(re, X, W, hr);
#pragma unroll
        for (int k = 0; k < 5; k++) { f[k] = hs[k]; f[5 + k] = hr[k]; }
    } else {
#pragma unroll
        for (int k = 0; k < 5; k++) { f[k] = H[se * 5 + k]; f[5 + k] = H[re * 5 + k]; }
    }

    float gc[9], gs[9];                          // gate trig th_e[10..18]
#pragma unroll
    for (int j = 0; j < 9; j++) {
        float h = 0.5f * th_e[10 + j];
        gs[j] = __sinf(h); gc[j] = __cosf(h);
    }

    float ev = edge_ev(lane, f, th_e, gc, gs);

    if constexpr (MODE == 2) {
        if (lane == 0) out[e] = ev;
    } else {
        if (lane < 10) EW[e * 10 + lane] = ev * f[lane];
    }
}

// ---------------------------------------------------------------------------
// node kernel, 4 nodes/block (r15-verified), 96 blocks, one CU round.
// Gather-reduce replaces atomics. FIRST=1: H computed inline from X,W.
//   packed m1,2,4,8,16 = {w10,w5,w2,w13,w3}; comp = w14
//   lane m1..m32 = {w7,w1,w0,w6,w4,w11}
// ---------------------------------------------------------------------------
template <int FIRST>
__global__ __launch_bounds__(256) void node_kernel(
    const float* __restrict__ H,
    const float* __restrict__ X, const float* __restrict__ W,
    const int* __restrict__ snd, const int* __restrict__ rcv,
    const float* __restrict__ EW,
    const float* __restrict__ th_n, float* __restrict__ Hout)
{
    const int n = blockIdx.x * 4 + (threadIdx.x >> 6);
    const int lane = threadIdx.x & 63;

    // gather incident-edge contributions
    float mi[5] = {0.f, 0.f, 0.f, 0.f, 0.f};
    float mo[5] = {0.f, 0.f, 0.f, 0.f, 0.f};
#pragma unroll
    for (int c = 0; c < N_EDGES / 64; c++) {
        int e = lane + c * 64;
        int se = snd[e], re = rcv[e];
        if (re == n) {
#pragma unroll
            for (int k = 0; k < 5; k++) mi[k] += EW[e * 10 + k];
        }
        if (se == n) {
#pragma unroll
            for (int k = 0; k < 5; k++) mo[k] += EW[e * 10 + 5 + k];
        }
    }
#pragma unroll
    for (int o = 32; o > 0; o >>= 1) {
#pragma unroll
        for (int k = 0; k < 5; k++) {
            mi[k] += __shfl_xor(mi[k], o, 64);
            mo[k] += __shfl_xor(mo[k], o, 64);
        }
    }

    // H values for wires 10-14
    float hv[5];
    if constexpr (FIRST) {
        h0_of(n, X, W, hv);
    } else {
#pragma unroll
        for (int k = 0; k < 5; k++) hv[k] = H[n * 5 + k];
    }

    // absorbed-RY base angles per PHYSICAL bit (wire_of_pb = {10,5,2,13,3,14,7,1,0,6,4,11})
    float cw[12], sw[12];
    {
        const float base[12] = {hv[0], mo[0], mi[2], hv[3], mi[3], hv[4],
                                mo[2], mi[1], mi[0], mo[1], mi[4], hv[1]};
        const int thw[12] = {10, 5, 2, 13, 3, 14, 7, 1, 0, 6, 4, 11};
#pragma unroll
        for (int pb = 0; pb < 12; pb++) {
            float h = 0.5f * (base[pb] + th_n[thw[pb]]);
            sw[pb] = __sinf(h);
            cw[pb] = __cosf(h);
        }
    }

    // gate trig (r11/r12-verified angles, incl. merged sums)
    float h_;
    h_ = 0.5f * th_n[15];                float gs15 = __sinf(h_), gc15 = __cosf(h_);
    h_ = 0.5f * th_n[16];                float gs16 = __sinf(h_), gc16 = __cosf(h_);
    h_ = 0.5f * th_n[14];                float gs14 = __sinf(h_), gc14 = __cosf(h_);
    h_ = 0.5f * th_n[19];                float gs19 = __sinf(h_), gc19 = __cosf(h_);
    h_ = 0.5f * th_n[20];                float gs20 = __sinf(h_), gc20 = __cosf(h_);
    h_ = 0.5f * th_n[25];                float gs25 = __sinf(h_), gc25 = __cosf(h_);
    h_ = 0.5f * th_n[29];                float gs29 = __sinf(h_), gc29 = __cosf(h_);
    h_ = 0.5f * th_n[30];                float gs30 = __sinf(h_), gc30 = __cosf(h_);
    h_ = 0.5f * (th_n[17] + th_n[21]);   float ms1721 = __sinf(h_), mc1721 = __cosf(h_);
    h_ = 0.5f * (th_n[18] + th_n[22]);   float ms1822 = __sinf(h_), mc1822 = __cosf(h_);
    h_ = 0.5f * (th_n[19] + th_n[28]);   float ms1928 = __sinf(h_), mc1928 = __cosf(h_);
    h_ = 0.5f * (th_n[23] + th_n[26]);   float ms2326 = __sinf(h_), mc2326 = __cosf(h_);
    h_ = 0.5f * (th_n[24] + th_n[27]);   float ms2427 = __sinf(h_), mc2427 = __cosf(h_);

    // product state: lane bits pb6..11 = {w7,w1,w0,w6,w4,w11},
    // packed pb0..4 = {w10,w5,w2,w13,w3}, comp pb5 = w14
    float pw = 1.f;
    pw *= (lane & 1)  ? sw[6]  : cw[6];
    pw *= (lane & 2)  ? sw[7]  : cw[7];
    pw *= (lane & 4)  ? sw[8]  : cw[8];
    pw *= (lane & 8)  ? sw[9]  : cw[9];
    pw *= (lane & 16) ? sw[10] : cw[10];
    pw *= (lane & 32) ? sw[11] : cw[11];
    float2 a[32];
#pragma unroll
    for (int k = 0; k < 32; k++) {
        float p = pw;
        p *= (k & 1)  ? sw[0] : cw[0];
        p *= (k & 2)  ? sw[1] : cw[1];
        p *= (k & 4)  ? sw[2] : cw[2];
        p *= (k & 8)  ? sw[3] : cw[3];
        p *= (k & 16) ? sw[4] : cw[4];
        a[k].x = p * cw[5];                     // component = w14
        a[k].y = p * sw[5];
    }

    cxl2<32, 2>(a, (lane & 4) != 0);             // cx(0,1)   tgt w1 (DPP)
    cxrr2<32, 16, 4>(a);                         // cx(3,2)   ctrl w3 pk-m16
    cxr2<32, 2>(a, (lane & 16) != 0);            // cx(4,5)   ctrl w4 m16
    cxl2<32, 8>(a, (lane & 1) != 0);             // cx(7,6)   ctrl w7 m1
    cxr2<32, 1>(a, (lane & 32) != 0);            // cx(11,10) ctrl w11 m32
    ryl2<32, 2>(a, lane, gc15, gs15);            // ry(15,w1) (DPP)
    ryr2<32, 4>(a, gc16, gs16);                  // ry(16,w2)
    cxr2<32, 4>(a, (lane & 2) != 0);             // cx(1,2)
    ryr2<32, 2>(a, gc14, gs14);                  // ry(14,w5)
    ryl2<32, 8>(a, lane, gc15, gs15);            // ry(15,w6) (DPP)
    cxr2<32, 2>(a, (lane & 8) != 0);             // cx(6,5)
    ryr2<32, 1>(a, mc1721, ms1721);              // ry(17+21,w10)
    ryr2<32, 8>(a, mc1822, ms1822);              // ry(18+22,w13)
    ryc2<32>(a, mc1928, ms1928);                 // ry(19+28,w14)
    ryr2<32, 4>(a, gc19, gs19);                  // ry(19,w2)
    ryr2<32, 2>(a, gc20, gs20);                  // ry(20,w5)
    cxrr2<32, 4, 2>(a);                          // cx(2,5)
    cxrr2<32, 8, 1>(a);                          // cx(13,10)
    ryr2<32, 2>(a, mc2326, ms2326);              // ry(23+26,w5)
    ryr2<32, 1>(a, mc2427, ms2427);              // ry(24+27,w10)
    ryl2<32, 4>(a, lane, gc25, gs25);            // ry(25,w0) shfl
    cxr2<32, 2>(a, (lane & 4) != 0);             // cx(0,5)
    cxcr2<32, 1>(a);                             // cx(14,10)
    ryr2<32, 2>(a, gc29, gs29);                  // ry(29,w5)
    ryr2<32, 1>(a, gc30, gs30);                  // ry(30,w10)

    // expz: wire5 -> packed m2, wire10 -> packed m1
    float z5 = 0.f, z10 = 0.f;
#pragma unroll
    for (int k = 0; k < 32; k++) {
        float v = a[k].x * a[k].x + a[k].y * a[k].y;
        z5  += (k & 2) ? -v : v;
        z10 += (k & 1) ? -v : v;
    }
#pragma unroll
    for (int o = 32; o > 0; o >>= 1) {
        z5  += __shfl_xor(z5, o, 64);
        z10 += __shfl_xor(z10, o, 64);
    }
    if (lane == 0) {
        const float PI_ = 3.14159265358979323846f;
        Hout[n * 5 + 0] = PI_ * (1.f - z5);
        Hout[n * 5 + 1] = PI_ * (1.f - z10);
        Hout[n * 5 + 2] = X[n * 3 + 0];
        Hout[n * 5 + 3] = X[n * 3 + 1];
        Hout[n * 5 + 4] = X[n * 3 + 2];
    }
}

// ---------------------------------------------------------------------------
extern "C" void kernel_launch(void* const* d_in, const int* in_sizes, int n_in,
                              void* d_out, int out_size, void* d_ws, size_t ws_size,
                              hipStream_t stream)
{
    const float* X    = (const float*)d_in[0];
    const float* Ri   = (const float*)d_in[1];
    const float* Ro   = (const float*)d_in[2];
    const float* W    = (const float*)d_in[3];
    const float* th_e = (const float*)d_in[4];
    const float* th_n = (const float*)d_in[5];
    float* out = (float*)d_out;

    int*   snd = (int*)d_ws;                // 1280
    int*   rcv = snd + N_EDGES;             // 1280
    float* EW  = (float*)(rcv + N_EDGES);   // 12800
    float* Hb  = EW + N_EDGES * 10;         // 1920
    float* Ha2 = Hb + N_NODES * 5;          // 1920

    // D: coalesced one-hot decode (r12-prep style)
    decode_kernel<<<240, 256, 0, stream>>>(Ri, Ro, snd, rcv);
    // E1: inline H0 + circuit -> EW
    edge_kernel<0><<<N_EDGES / 8, 512, 0, stream>>>(
        nullptr, X, W, snd, rcv, th_e, EW, nullptr);
    // N1: inline H0 + gather EW -> Hb
    node_kernel<1><<<N_NODES / 4, 256, 0, stream>>>(
        nullptr, X, W, snd, rcv, EW, th_n, Hb);
    // E2: Hb -> EW
    edge_kernel<1><<<N_EDGES / 8, 512, 0, stream>>>(
        Hb, X, W, snd, rcv, th_e, EW, nullptr);
    // N2: Hb + gather EW -> Ha2
    node_kernel<0><<<N_NODES / 4, 256, 0, stream>>>(
        Hb, X, W, snd, rcv, EW, th_n, Ha2);
    // E3: Ha2 -> out (final)
    edge_kernel<2><<<N_EDGES / 8, 512, 0, stream>>>(
        Ha2, X, W, snd, rcv, th_e, nullptr, out);
}

// Round 17
// 38.538 us; speedup vs baseline: 4.0052x; 1.3042x over previous
//
#include <hip/hip_runtime.h>
#include <math.h>

#define N_NODES 384
#define N_EDGES 1280

// ---------------------------------------------------------------------------
// Lane-exchange: DPP for xor masks 1,2,8 (VALU pipe, verified r6-r12):
//   xor1 = quad_perm [1,0,3,2]; xor2 = quad_perm [2,3,0,1]; xor8 = row_ror:8.
// Masks 4,16,32 -> __shfl_xor. Permlane swaps: BANNED (r3/r4 failures).
// Cooperative grid.sync: BANNED (r14: ~30us/sync). EW-gather: BANNED (r15/16).
// ---------------------------------------------------------------------------
template <int M>
__device__ __forceinline__ float lxor_f(float x)
{
    if constexpr (M == 1) {
        return __builtin_bit_cast(float, __builtin_amdgcn_mov_dpp(
            __builtin_bit_cast(int, x), 0xB1, 0xF, 0xF, true));
    } else if constexpr (M == 2) {
        return __builtin_bit_cast(float, __builtin_amdgcn_mov_dpp(
            __builtin_bit_cast(int, x), 0x4E, 0xF, 0xF, true));
    } else if constexpr (M == 8) {
        return __builtin_bit_cast(float, __builtin_amdgcn_mov_dpp(
            __builtin_bit_cast(int, x), 0x128, 0xF, 0xF, true));
    } else {
        return __shfl_xor(x, M, 64);        // masks 4, 16, 32
    }
}

// ---------------------------------------------------------------------------
// float2-packed gate helpers (r8/r11/r12-verified algebra).
// ---------------------------------------------------------------------------
template <int K, int M>         // RY on a packed-index bit (elementwise f2)
__device__ __forceinline__ void ryr2(float2 (&a)[K], float c_, float s_)
{
#pragma unroll
    for (int k = 0; k < K; k++)
        if ((k & M) == 0) {
            float2 u = a[k], v = a[k | M];
            a[k].x     = c_ * u.x - s_ * v.x;
            a[k].y     = c_ * u.y - s_ * v.y;
            a[k | M].x = s_ * u.x + c_ * v.x;
            a[k | M].y = s_ * u.y + c_ * v.y;
        }
}

template <int K>                // RY on the component bit (x/y rotate)
__device__ __forceinline__ void ryc2(float2 (&a)[K], float c_, float s_)
{
#pragma unroll
    for (int k = 0; k < K; k++) {
        float x = a[k].x, y = a[k].y;
        a[k].x = c_ * x - s_ * y;
        a[k].y = s_ * x + c_ * y;
    }
}

template <int K, int LM>        // RY on a lane bit
__device__ __forceinline__ void ryl2(float2 (&a)[K], int lane, float c_, float s_)
{
    const float ss = (lane & LM) ? s_ : -s_;
#pragma unroll
    for (int k = 0; k < K; k++) {
        float ox = lxor_f<LM>(a[k].x);
        float oy = lxor_f<LM>(a[k].y);
        a[k].x = fmaf(ss, ox, c_ * a[k].x);
        a[k].y = fmaf(ss, oy, c_ * a[k].y);
    }
}

template <int K, int TM>        // CX, bool ctrl, lane-bit target
__device__ __forceinline__ void cxl2(float2 (&a)[K], bool ctrl)
{
#pragma unroll
    for (int k = 0; k < K; k++) {
        float ox = lxor_f<TM>(a[k].x);
        float oy = lxor_f<TM>(a[k].y);
        a[k].x = ctrl ? ox : a[k].x;
        a[k].y = ctrl ? oy : a[k].y;
    }
}

template <int K, int TM>        // CX, bool ctrl, packed-index target
__device__ __forceinline__ void cxr2(float2 (&a)[K], bool ctrl)
{
#pragma unroll
    for (int k = 0; k < K; k++)
        if ((k & TM) == 0) {
            float2 u = a[k], v = a[k | TM];
            a[k].x      = ctrl ? v.x : u.x;
            a[k].y      = ctrl ? v.y : u.y;
            a[k | TM].x = ctrl ? u.x : v.x;
            a[k | TM].y = ctrl ? u.y : v.y;
        }
}

template <int K>                // CX, bool ctrl, COMPONENT target (x<->y)
__device__ __forceinline__ void cxc2(float2 (&a)[K], bool ctrl)
{
#pragma unroll
    for (int k = 0; k < K; k++) {
        float x = a[k].x, y = a[k].y;
        a[k].x = ctrl ? y : x;
        a[k].y = ctrl ? x : y;
    }
}

template <int K, int CM, int TM>  // CX, packed ctrl + packed target (rename)
__device__ __forceinline__ void cxrr2(float2 (&a)[K])
{
#pragma unroll
    for (int k = 0; k < K; k++)
        if ((k & CM) && !(k & TM)) {
            float2 t = a[k]; a[k] = a[k | TM]; a[k | TM] = t;
        }
}

template <int K, int TM>        // CX, ctrl = COMPONENT bit, packed target
__device__ __forceinline__ void cxcr2(float2 (&a)[K])
{
#pragma unroll
    for (int k = 0; k < K; k++)
        if ((k & TM) == 0) {    // swap y-components (ctrl=1 amps) across TM
            float t = a[k].y; a[k].y = a[k | TM].y; a[k | TM].y = t;
        }
}

// ---------------------------------------------------------------------------
// prep: float4-coalesced one-hot decode (r16-verified pattern) + H0 + theta
// trig tables + zero M. 480 blocks x 256 threads (was 1920 scalar blocks).
// Side jobs byte-identical to r12.
// ---------------------------------------------------------------------------
__global__ __launch_bounds__(256) void prep_kernel(
    const float* __restrict__ X, const float* __restrict__ Ri,
    const float* __restrict__ Ro, const float* __restrict__ W,
    const float* __restrict__ th_e, const float* __restrict__ th_n,
    int* __restrict__ snd, int* __restrict__ rcv, float* __restrict__ H0,
    float* __restrict__ cte, float* __restrict__ ste,
    float* __restrict__ ctn, float* __restrict__ stn,
    float* __restrict__ M)
{
    int idx = blockIdx.x * blockDim.x + threadIdx.x;    // 0..122879
    {
        const float4* Ro4 = (const float4*)Ro;
        const float4* Ri4 = (const float4*)Ri;
        int n  = (idx * 4) / N_EDGES;
        int e0 = (idx * 4) % N_EDGES;                   // 1280 % 4 == 0: row-safe
        float4 ro = Ro4[idx];
        float4 ri = Ri4[idx];
        if (ro.x > 0.5f) snd[e0 + 0] = n;
        if (ro.y > 0.5f) snd[e0 + 1] = n;
        if (ro.z > 0.5f) snd[e0 + 2] = n;
        if (ro.w > 0.5f) snd[e0 + 3] = n;
        if (ri.x > 0.5f) rcv[e0 + 0] = n;
        if (ri.y > 0.5f) rcv[e0 + 1] = n;
        if (ri.z > 0.5f) rcv[e0 + 2] = n;
        if (ri.w > 0.5f) rcv[e0 + 3] = n;
    }
    if (idx < N_NODES) {
        int n = idx;
        float x0 = X[n * 3 + 0], x1 = X[n * 3 + 1], x2 = X[n * 3 + 2];
        float t0 = x0 * W[0] + x1 * W[2] + x2 * W[4];
        float t1 = x0 * W[1] + x1 * W[3] + x2 * W[5];
        const float TP = 6.2831853071795864769f;
        H0[n * 5 + 0] = TP / (1.f + __expf(-t0));
        H0[n * 5 + 1] = TP / (1.f + __expf(-t1));
        H0[n * 5 + 2] = x0;
        H0[n * 5 + 3] = x1;
        H0[n * 5 + 4] = x2;
    } else if (idx >= 512 && idx < 512 + 19) {
        int j = idx - 512;
        float h = 0.5f * th_e[j];
        cte[j] = __cosf(h); ste[j] = __sinf(h);
    } else if (idx >= 576 && idx < 576 + 31) {
        int j = idx - 576;
        float h = 0.5f * th_n[j];
        ctn[j] = __cosf(h); stn[j] = __sinf(h);
    } else if (idx >= 1024 && idx < 1024 + N_NODES * 10) {
        M[idx - 1024] = 0.f;
    }
}

// ---------------------------------------------------------------------------
// edge circuit (r8/r11/r12-verified, UNCHANGED). 4 edges/block, 8 float2/lane.
//   lane bits: m1=w1, m2=w0, m4=w3, m8=w5, m16=w6, m32=w8
//   packed-index bits: m1=w7, m2=w2, m4=w4;  component = w9
// ---------------------------------------------------------------------------
__global__ __launch_bounds__(256) void edge_kernel(
    const float* __restrict__ H, const int* __restrict__ snd, const int* __restrict__ rcv,
    const float* __restrict__ cte, const float* __restrict__ ste,
    const float* __restrict__ th_e,
    float* __restrict__ out, float* __restrict__ M, int do_agg)
{
    const int e = blockIdx.x * 4 + (threadIdx.x >> 6);
    const int lane = threadIdx.x & 63;
    const int se = snd[e], re = rcv[e];

    float f[10];
#pragma unroll
    for (int k = 0; k < 5; k++) { f[k] = H[se * 5 + k]; f[5 + k] = H[re * 5 + k]; }

    float cw[10], sw[10];
#pragma unroll
    for (int w = 0; w < 10; w++) {
        float h = 0.5f * (f[w] + th_e[w]);      // absorbed first RY
        sw[w] = __sinf(h);
        cw[w] = __cosf(h);
    }

    float pl = 1.f;
    pl *= (lane & 1)  ? sw[1] : cw[1];
    pl *= (lane & 2)  ? sw[0] : cw[0];
    pl *= (lane & 4)  ? sw[3] : cw[3];
    pl *= (lane & 8)  ? sw[5] : cw[5];
    pl *= (lane & 16) ? sw[6] : cw[6];
    pl *= (lane & 32) ? sw[8] : cw[8];
    float2 a[8];
#pragma unroll
    for (int k = 0; k < 8; k++) {
        float p = pl;
        p *= (k & 1) ? sw[7] : cw[7];
        p *= (k & 2) ? sw[2] : cw[2];
        p *= (k & 4) ? sw[4] : cw[4];
        a[k].x = p * cw[9];
        a[k].y = p * sw[9];
    }

    cxl2<8, 1>(a, (lane & 2) != 0);              // cx(0,1)
    cxr2<8, 2>(a, (lane & 4) != 0);              // cx(3,2)
    cxr2<8, 4>(a, (lane & 8) != 0);              // cx(5,4)
    cxr2<8, 1>(a, (lane & 16) != 0);             // cx(6,7)
    cxc2<8>(a, (lane & 32) != 0);                // cx(8,9)
    ryl2<8, 1>(a, lane, cte[10], ste[10]);       // ry(10,w1)
    ryr2<8, 2>(a, cte[11], ste[11]);             // ry(11,w2)
    cxr2<8, 2>(a, (lane & 1) != 0);              // cx(1,2)
    ryr2<8, 1>(a, cte[12], ste[12]);             // ry(12,w7)
    ryc2<8>(a, cte[13], ste[13]);                // ry(13,w9)
    cxcr2<8, 1>(a);                              // cx(9,7)
    ryr2<8, 2>(a, cte[14], ste[14]);             // ry(14,w2)
    ryr2<8, 4>(a, cte[15], ste[15]);             // ry(15,w4)
    cxrr2<8, 2, 4>(a);                           // cx(2,4)
    ryr2<8, 4>(a, cte[16], ste[16]);             // ry(16,w4)
    ryr2<8, 1>(a, cte[17], ste[17]);             // ry(17,w7)
    cxrr2<8, 4, 1>(a);                           // cx(4,7)
    ryr2<8, 1>(a, cte[18], ste[18]);             // ry(18,w7)

    float z = 0.f;
#pragma unroll
    for (int k = 0; k < 8; k++) {
        float v = a[k].x * a[k].x + a[k].y * a[k].y;
        z += (k & 1) ? -v : v;
    }
#pragma unroll
    for (int o = 32; o > 0; o >>= 1) z += __shfl_xor(z, o, 64);
    float ev = 0.5f * (1.f - z);

    if (lane == 0) out[e] = ev;
    if (do_agg) {
        if (lane < 5)       atomicAdd(&M[re * 10 + lane], ev * f[lane]);
        else if (lane < 10) atomicAdd(&M[se * 10 + lane], ev * f[lane]);
    }
}

// ---------------------------------------------------------------------------
// node circuit (r12-verified, UNCHANGED): 12 effective qubits, ONE WAVE PER
// NODE, 4096 amps = 64 lanes x 32 float2.
//   packed m1,2,4,8 = {w10,w5,w2,w13}, packed m16 = w3 (ctrl-only)
//   comp = w14; lane m2=w1, m4=w0, m8=w6; m1=w7, m16=w4, m32=w11 (ctrl-only)
// Read -> __syncthreads (vmcnt drain) -> zero-M structure kept verbatim.
// ---------------------------------------------------------------------------
__global__ __launch_bounds__(64) void node_kernel(
    const float* __restrict__ H, float* __restrict__ M,
    const float* __restrict__ ctn, const float* __restrict__ stn,
    const float* __restrict__ th_n,
    const float* __restrict__ X, float* __restrict__ Hout)
{
    const int n = blockIdx.x;
    const int tid = threadIdx.x;
    const int lane = tid;                       // one wave

    __shared__ float cw[12], sw[12];            // indexed by PHYSICAL bit

    if (tid < 12) {
        const int wire_of_pb[12] = {10, 5, 2, 13, 3, 14, 7, 1, 0, 6, 4, 11};
        int w_ = wire_of_pb[tid];
        float ang = ((w_ < 10) ? M[n * 10 + w_] : H[n * 5 + (w_ - 10)]) + th_n[w_];
        float h = 0.5f * ang;                   // absorbed first RY
        sw[tid] = __sinf(h);
        cw[tid] = __cosf(h);
    }
    __syncthreads();                            // vmcnt drain: M reads complete
    if (tid < 10) M[n * 10 + tid] = 0.f;        // re-zero own row for next edge pass

    // merged-gate trig (r11-verified values)
    float h1721 = 0.5f * (th_n[17] + th_n[21]);
    float h1822 = 0.5f * (th_n[18] + th_n[22]);
    float h1928 = 0.5f * (th_n[19] + th_n[28]);
    float h2326 = 0.5f * (th_n[23] + th_n[26]);
    float h2427 = 0.5f * (th_n[24] + th_n[27]);
    float ms1721 = __sinf(h1721), mc1721 = __cosf(h1721);
    float ms1822 = __sinf(h1822), mc1822 = __cosf(h1822);
    float ms1928 = __sinf(h1928), mc1928 = __cosf(h1928);
    float ms2326 = __sinf(h2326), mc2326 = __cosf(h2326);
    float ms2427 = __sinf(h2427), mc2427 = __cosf(h2427);

    // product state: lane bits pb6..11 = {w7,w1,w0,w6,w4,w11},
    // packed pb0..4 = {w10,w5,w2,w13,w3}, comp pb5 = w14
    float pw = 1.f;
    pw *= (lane & 1)  ? sw[6]  : cw[6];
    pw *= (lane & 2)  ? sw[7]  : cw[7];
    pw *= (lane & 4)  ? sw[8]  : cw[8];
    pw *= (lane & 8)  ? sw[9]  : cw[9];
    pw *= (lane & 16) ? sw[10] : cw[10];
    pw *= (lane & 32) ? sw[11] : cw[11];
    float2 a[32];
#pragma unroll
    for (int k = 0; k < 32; k++) {
        float p = pw;
        p *= (k & 1)  ? sw[0] : cw[0];
        p *= (k & 2)  ? sw[1] : cw[1];
        p *= (k & 4)  ? sw[2] : cw[2];
        p *= (k & 8)  ? sw[3] : cw[3];
        p *= (k & 16) ? sw[4] : cw[4];
        a[k].x = p * cw[5];                     // component = w14
        a[k].y = p * sw[5];
    }

    cxl2<32, 2>(a, (lane & 4) != 0);             // cx(0,1)   tgt w1 (DPP)
    cxrr2<32, 16, 4>(a);                         // cx(3,2)   ctrl w3 pk-m16
    cxr2<32, 2>(a, (lane & 16) != 0);            // cx(4,5)   ctrl w4 m16
    cxl2<32, 8>(a, (lane & 1) != 0);             // cx(7,6)   ctrl w7 m1
    cxr2<32, 1>(a, (lane & 32) != 0);            // cx(11,10) ctrl w11 m32
    ryl2<32, 2>(a, lane, ctn[15], stn[15]);      // ry(15,w1) (DPP)
    ryr2<32, 4>(a, ctn[16], stn[16]);            // ry(16,w2)
    cxr2<32, 4>(a, (lane & 2) != 0);             // cx(1,2)
    ryr2<32, 2>(a, ctn[14], stn[14]);            // ry(14,w5)
    ryl2<32, 8>(a, lane, ctn[15], stn[15]);      // ry(15,w6) (DPP)
    cxr2<32, 2>(a, (lane & 8) != 0);             // cx(6,5)
    ryr2<32, 1>(a, mc1721, ms1721);              // ry(17+21,w10)
    ryr2<32, 8>(a, mc1822, ms1822);              // ry(18+22,w13)
    ryc2<32>(a, mc1928, ms1928);                 // ry(19+28,w14)
    ryr2<32, 4>(a, ctn[19], stn[19]);            // ry(19,w2)
    ryr2<32, 2>(a, ctn[20], stn[20]);            // ry(20,w5)
    cxrr2<32, 4, 2>(a);                          // cx(2,5)
    cxrr2<32, 8, 1>(a);                          // cx(13,10)
    ryr2<32, 2>(a, mc2326, ms2326);              // ry(23+26,w5)
    ryr2<32, 1>(a, mc2427, ms2427);              // ry(24+27,w10)
    ryl2<32, 4>(a, lane, ctn[25], stn[25]);      // ry(25,w0) shfl
    cxr2<32, 2>(a, (lane & 4) != 0);             // cx(0,5)
    cxcr2<32, 1>(a);                             // cx(14,10)
    ryr2<32, 2>(a, ctn[29], stn[29]);            // ry(29,w5)
    ryr2<32, 1>(a, ctn[30], stn[30]);            // ry(30,w10)

    // expz: wire5 -> packed m2, wire10 -> packed m1
    float z5 = 0.f, z10 = 0.f;
#pragma unroll
    for (int k = 0; k < 32; k++) {
        float v = a[k].x * a[k].x + a[k].y * a[k].y;
        z5  += (k & 2) ? -v : v;
        z10 += (k & 1) ? -v : v;
    }
#pragma unroll
    for (int o = 32; o > 0; o >>= 1) {
        z5  += __shfl_xor(z5, o, 64);
        z10 += __shfl_xor(z10, o, 64);
    }
    if (lane == 0) {
        const float PI_ = 3.14159265358979323846f;
        Hout[n * 5 + 0] = PI_ * (1.f - z5);
        Hout[n * 5 + 1] = PI_ * (1.f - z10);
        Hout[n * 5 + 2] = X[n * 3 + 0];
        Hout[n * 5 + 3] = X[n * 3 + 1];
        Hout[n * 5 + 4] = X[n * 3 + 2];
    }
}

// ---------------------------------------------------------------------------
extern "C" void kernel_launch(void* const* d_in, const int* in_sizes, int n_in,
                              void* d_out, int out_size, void* d_ws, size_t ws_size,
                              hipStream_t stream)
{
    const float* X    = (const float*)d_in[0];
    const float* Ri   = (const float*)d_in[1];
    const float* Ro   = (const float*)d_in[2];
    const float* W    = (const float*)d_in[3];
    const float* th_e = (const float*)d_in[4];
    const float* th_n = (const float*)d_in[5];
    float* out = (float*)d_out;

    float* Ha  = (float*)d_ws;              // 1920
    float* Hb  = Ha + N_NODES * 5;          // 1920
    float* ev  = Hb + N_NODES * 5;          // 1280
    int*   snd = (int*)(ev + N_EDGES);      // 1280
    int*   rcv = snd + N_EDGES;             // 1280
    float* M   = (float*)(rcv + N_EDGES);   // 3840
    float* cte = M + N_NODES * 10;          // 19
    float* ste = cte + 19;                  // 19
    float* ctn = ste + 19;                  // 31
    float* stn = ctn + 31;                  // 31

    prep_kernel<<<(N_NODES * N_EDGES / 4 + 255) / 256, 256, 0, stream>>>(
        X, Ri, Ro, W, th_e, th_n, snd, rcv, Ha, cte, ste, ctn, stn, M);

    edge_kernel<<<N_EDGES / 4, 256, 0, stream>>>(Ha, snd, rcv, cte, ste, th_e, ev, M, 1);
    node_kernel<<<N_NODES, 64, 0, stream>>>(Ha, M, ctn, stn, th_n, X, Hb);

    edge_kernel<<<N_EDGES / 4, 256, 0, stream>>>(Hb, snd, rcv, cte, ste, th_e, ev, M, 1);
    node_kernel<<<N_NODES, 64, 0, stream>>>(Hb, M, ctn, stn, th_n, X, Ha);

    edge_kernel<<<N_EDGES / 4, 256, 0, stream>>>(Ha, snd, rcv, cte, ste, th_e, out, M, 0);
}